// Round 1
// 80.172 us; speedup vs baseline: 1.0232x; 1.0232x over previous
//
#include <hip/hip_runtime.h>

// QuantumKernelLayer: out[b,c] = | prod_j cos(0.5*(x[b,j] - centers[c,j])) |
// B=8192, C=2048, N=8 (fp32 in, fp32 out).
//
// cos((x-c)/2) = cos(x/2)cos(c/2) + sin(x/2)sin(c/2): transcendentals in the
// prologue only; inner loop is pure mul/FMA.
//
// R1 change vs 82.5us baseline: register diet for occupancy.
//   CPT 4 -> 2 : center cos/sin = 32 VGPRs (was 64), total live ~55.
//   __launch_bounds__(256, 8): cap at 64 VGPR -> 8 waves/SIMD (was 4, or 2 if
//   the old kernel sat in the (128,256] VGPR bucket / spilled).
//   Grid doubles to 2048 blocks (8 blocks/CU).
//   Per-row x cos/sin read as 4x ds_read_b128 (broadcast, conflict-free).

#define TPB  256
#define ROWS 16      // batch rows per block
#define CPT  2       // centers per thread
#define NW   8       // wires

__global__ __launch_bounds__(TPB, 8) void quantum_fidelity_kernel(
    const float* __restrict__ x,        // [B, 8]
    const float* __restrict__ centers,  // [C, 8]
    float* __restrict__ out,            // [B, C]
    int C) {
  __shared__ __align__(16) float2 xs[ROWS * NW];  // (cos, sin) of x/2

  const int t = threadIdx.x;
  const int row0 = blockIdx.y * ROWS;
  const int c0 = (blockIdx.x * TPB + t) * CPT;

  // Stage cos/sin of the 16 rows' x values (128 elements) into LDS.
  if (t < ROWS * NW) {
    float h = 0.5f * x[(size_t)row0 * NW + t];
    xs[t] = make_float2(__cosf(h), __sinf(h));
  }

  // cos/sin of this thread's 2 consecutive centers (16 contiguous floats).
  float cc0[NW], sc0[NW], cc1[NW], sc1[NW];
  {
    const float4* cp = reinterpret_cast<const float4*>(centers + (size_t)c0 * NW);
    float4 a = cp[0], b = cp[1], c = cp[2], d = cp[3];
    float v0[NW] = {a.x, a.y, a.z, a.w, b.x, b.y, b.z, b.w};
    float v1[NW] = {c.x, c.y, c.z, c.w, d.x, d.y, d.z, d.w};
#pragma unroll
    for (int j = 0; j < NW; ++j) {
      float h0 = 0.5f * v0[j];
      cc0[j] = __cosf(h0);
      sc0[j] = __sinf(h0);
      float h1 = 0.5f * v1[j];
      cc1[j] = __cosf(h1);
      sc1[j] = __sinf(h1);
    }
  }
  __syncthreads();

  const float4* xsv = reinterpret_cast<const float4*>(xs);  // 2 wires per read
  float2* orow = reinterpret_cast<float2*>(out + (size_t)row0 * C + c0);
  const int ostride = C / 2;  // float2 per output row

#pragma unroll 1
  for (int r = 0; r < ROWS; ++r) {
    float p0, p1;
#pragma unroll
    for (int jj = 0; jj < 4; ++jj) {
      float4 q = xsv[r * 4 + jj];  // (cx0, sx0, cx1, sx1) for wires 2jj, 2jj+1
      float a0 = fmaf(sc0[2 * jj],     q.y, cc0[2 * jj]     * q.x);
      float b0 = fmaf(sc0[2 * jj + 1], q.w, cc0[2 * jj + 1] * q.z);
      float a1 = fmaf(sc1[2 * jj],     q.y, cc1[2 * jj]     * q.x);
      float b1 = fmaf(sc1[2 * jj + 1], q.w, cc1[2 * jj + 1] * q.z);
      float m0 = a0 * b0;
      float m1 = a1 * b1;
      if (jj == 0) { p0 = m0; p1 = m1; }
      else         { p0 *= m0; p1 *= m1; }
    }
    orow[(size_t)r * ostride] = make_float2(fabsf(p0), fabsf(p1));
  }
}

extern "C" void kernel_launch(void* const* d_in, const int* in_sizes, int n_in,
                              void* d_out, int out_size, void* d_ws, size_t ws_size,
                              hipStream_t stream) {
  const float* x = (const float*)d_in[0];
  const float* centers = (const float*)d_in[1];
  float* out = (float*)d_out;

  const int B = in_sizes[0] / NW;  // 8192
  const int C = in_sizes[1] / NW;  // 2048

  dim3 grid(C / (TPB * CPT), B / ROWS);  // (4, 512) = 2048 blocks, 8/CU
  quantum_fidelity_kernel<<<grid, TPB, 0, stream>>>(x, centers, out, C);
}